// Round 13
// baseline (158.030 us; speedup 1.0000x reference)
//
#include <hip/hip_runtime.h>
#include <hip/hip_bf16.h>
#include <stdint.h>

// Problem constants
#define B_  4096
#define T_  80
#define E_  100
#define U_  64
#define G_  256    // 4*U
#define V_  10000

#define S_H  80    // hW row stride (bf16): 160B rows, 16B aligned; b128 frag reads
                   // land banks 8*row+4*kg -> max 2-way (free, m136)
#define AS   136   // embk emb-tile LDS stride (bf16)
#define KS2  132   // embk k1-tile ROW-major LDS stride (bf16)
#define TS   81    // token LDS row stride (ints)
#define XS   264   // xstage row stride (floats): 1056B rows, 16B aligned; xk b128
                   // reads land banks 8*row+4*kg -> max 2-way (free)

typedef __attribute__((ext_vector_type(8))) __bf16 bf16x8;
typedef __attribute__((ext_vector_type(4))) __bf16 bf16x4;
typedef __attribute__((ext_vector_type(4))) float  floatx4;

__device__ __forceinline__ float sigmoidf_(float x) {
    return __builtin_amdgcn_rcpf(1.f + __expf(-x));
}

__device__ __forceinline__ float tanhf_(float x) {
    // 1 - 2/(e^{2x}+1): monotone, saturates correctly, no NaN
    return fmaf(-2.f, __builtin_amdgcn_rcpf(__expf(2.f * x) + 1.f), 1.f);
}

// global -> LDS direct DMA: each lane contributes 16B; LDS dest = wave-uniform
// base + lane*16 (linear). Tracked by (per-wave) vmcnt.
__device__ __forceinline__ void gload16(const float* gsrc, const float* ldst) {
    __builtin_amdgcn_global_load_lds(
        (const __attribute__((address_space(1))) void*)(uintptr_t)gsrc,
        (__attribute__((address_space(3))) void*)(uintptr_t)ldst,
        16, 0, 0);
}

#define MFMA16(A,B,C) __builtin_amdgcn_mfma_f32_16x16x32_bf16(A, B, C, 0, 0, 0)

// ---------------------------------------------------------------------------
// Kernel A (MFMA): embk[v][g] = b1[g] + emb[v] . k1[:,g]   (R5/R6, known-good)
// ---------------------------------------------------------------------------
__global__ __launch_bounds__(256) void embk_kernel(const float* __restrict__ emb,
                                                   const float* __restrict__ k1,
                                                   const float* __restrict__ b1,
                                                   float* __restrict__ embk) {
    __shared__ __bf16 aLDS[64 * AS];         // 17.4 KB  (emb tile, row-major)
    __shared__ __bf16 kLDS[128 * KS2];       // 33.8 KB  (k1 tile, ROW-major [k][col])

    const int tid  = threadIdx.x;
    const int lane = tid & 63;
    const int w    = tid >> 6;
    const int n    = lane & 15;
    const int kg   = lane >> 4;
    const int v0   = (blockIdx.x >> 1) * 64;
    const int n0   = (blockIdx.x & 1) * 128;
    const int nrows = min(64, V_ - v0);

    for (int i = tid; i < 64 * AS / 8; i += 256) {
        bf16x8 z;
#pragma unroll
        for (int jj = 0; jj < 8; ++jj) z[jj] = (__bf16)0.f;
        *(bf16x8*)(aLDS + i * 8) = z;
    }
    for (int i = tid; i < 28 * KS2; i += 256)
        kLDS[100 * KS2 + i] = (__bf16)0.f;

    const float bv0 = b1[n0 + w * 32 + n];
    const float bv1 = b1[n0 + w * 32 + 16 + n];

    __syncthreads();

    for (int i = tid; i < nrows * 25; i += 256) {
        int r = i / 25, q = i - r * 25;
        float4 ev = *(const float4*)(emb + (long)(v0 + r) * E_ + q * 4);
        bf16x4 bv; bv[0] = (__bf16)ev.x; bv[1] = (__bf16)ev.y;
                   bv[2] = (__bf16)ev.z; bv[3] = (__bf16)ev.w;
        *(bf16x4*)(aLDS + r * AS + q * 4) = bv;
    }
    for (int i = tid; i < 100 * 32; i += 256) {
        int k = i >> 5, cq = (i & 31) * 4;
        float4 kv = *(const float4*)(k1 + (long)k * G_ + n0 + cq);
        bf16x4 bv; bv[0] = (__bf16)kv.x; bv[1] = (__bf16)kv.y;
                   bv[2] = (__bf16)kv.z; bv[3] = (__bf16)kv.w;
        *(bf16x4*)(kLDS + k * KS2 + cq) = bv;
    }
    __syncthreads();

    bf16x8 bfr[2][4];
#pragma unroll
    for (int ct = 0; ct < 2; ++ct)
#pragma unroll
        for (int kc = 0; kc < 4; ++kc) {
            bf16x8 s;
#pragma unroll
            for (int jj = 0; jj < 8; ++jj)
                s[jj] = kLDS[(kc * 32 + kg * 8 + jj) * KS2 + w * 32 + ct * 16 + n];
            bfr[ct][kc] = s;
        }

#pragma unroll
    for (int mt = 0; mt < 4; ++mt) {
        const __bf16* ab = aLDS + (mt * 16 + n) * AS + kg * 8;
        bf16x8 a0 = *(const bf16x8*)(ab + 0);
        bf16x8 a1 = *(const bf16x8*)(ab + 32);
        bf16x8 a2 = *(const bf16x8*)(ab + 64);
        bf16x8 a3 = *(const bf16x8*)(ab + 96);
#pragma unroll
        for (int ct = 0; ct < 2; ++ct) {
            float bv = ct ? bv1 : bv0;
            floatx4 acc = {bv, bv, bv, bv};
            acc = MFMA16(a0, bfr[ct][0], acc);
            acc = MFMA16(a1, bfr[ct][1], acc);
            acc = MFMA16(a2, bfr[ct][2], acc);
            acc = MFMA16(a3, bfr[ct][3], acc);
#pragma unroll
            for (int r = 0; r < 4; ++r) {
                int v = v0 + mt * 16 + kg * 4 + r;
                if (v < V_) embk[(long)v * G_ + n0 + w * 32 + ct * 16 + n] = acc[r];
            }
        }
    }
}

// ---------------------------------------------------------------------------
// Kernel B (R13): BARRIER-FREE. Wave w owns batch rows w*4..w*4+3 end-to-end:
// all 256 gate cols via 16 r1^T col-tiles held in registers (32 MFMA/step),
// MFMA N=16 = 4 real rows x 4 mirrors (bit-identical cols; gate r-split
// across mirror lanes m=n>>2 -> 4 cells/lane, same trans work as R6).
// h lives in a WAVE-PRIVATE LDS row set: ds_write then same-wave ds_read
// (LDS is in-order within a wave) -> NO s_barrier anywhere. xk DMA is
// wave-private with counted per-wave vmcnt(4), 3-slot rotation.
// Per-output accumulation order (embk C-init -> 2 chained h-MFMAs) is
// identical to R6 -> bit-identical output.
// Removes from the chain: all-wave arrival skew, barrier release, pre-barrier
// drain couple, post-barrier 4-wave LDS burst (the invariant ~1700cy spine).
// ---------------------------------------------------------------------------
template<int RS, int WS>
__device__ __forceinline__ void lstm_step(
        int t, int lane, int n, int kg, int w, int m, int row,
        const int* __restrict__ tokW, __bf16* hW, float* xst,
        const bf16x8 (&afr)[16][2],
        const float* __restrict__ embk,
        float (&c)[4], int (&tk)[4]) {
    // slot RS's DMAs (issued at t-2) complete once <=4 (= t-1's) remain.
    asm volatile("s_waitcnt vmcnt(4)" ::: "memory");

    // issue DMA for t+2 into slot WS (tokens prefetched last step; slot WS
    // was read at t-1, reads completed before their MFMA use -> WAR-safe)
    if (t + 2 < T_) {
#pragma unroll
        for (int r = 0; r < 4; ++r)
            gload16(embk + (long)tk[r] * G_ + (lane << 2),
                    xst + WS * (16 * XS) + (w * 4 + r) * XS);
    }

    // h^T_{t-1} fragments from the wave's own rows (shared across all 16 tiles)
    const __bf16* hrow = hW + (w * 4 + row) * S_H;
    bf16x8 hb0 = *(const bf16x8*)(hrow + kg * 8);
    bf16x8 hb1 = *(const bf16x8*)(hrow + 32 + kg * 8);

    // prefetch tokens for next step's DMA (uniform scalars; latency spans step)
    if (t + 3 < T_) {
#pragma unroll
        for (int r = 0; r < 4; ++r)
            tk[r] = tokW[(w * 4 + r) * TS + (t + 3)];
    }

    const float* xrow = xst + RS * (16 * XS) + (w * 4 + row) * XS + kg * 4;

    // 4 independent unit-groups: tiles {ug, ug+4, ug+8, ug+12} = {i,f,g,o}
#pragma unroll
    for (int ug = 0; ug < 4; ++ug) {
        floatx4 ai = *(const floatx4*)(xrow + (ug +  0) * 16);
        floatx4 af = *(const floatx4*)(xrow + (ug +  4) * 16);
        floatx4 ag = *(const floatx4*)(xrow + (ug +  8) * 16);
        floatx4 ao = *(const floatx4*)(xrow + (ug + 12) * 16);
        ai = MFMA16(afr[ug +  0][0], hb0, ai); ai = MFMA16(afr[ug +  0][1], hb1, ai);
        af = MFMA16(afr[ug +  4][0], hb0, af); af = MFMA16(afr[ug +  4][1], hb1, af);
        ag = MFMA16(afr[ug +  8][0], hb0, ag); ag = MFMA16(afr[ug +  8][1], hb1, ag);
        ao = MFMA16(afr[ug + 12][0], hb0, ao); ao = MFMA16(afr[ug + 12][1], hb1, ao);

        // mirror lanes hold identical acc; this lane gates r = m (2-3 cndmask each)
        float zi = (m & 2) ? ((m & 1) ? ai[3] : ai[2]) : ((m & 1) ? ai[1] : ai[0]);
        float zf = (m & 2) ? ((m & 1) ? af[3] : af[2]) : ((m & 1) ? af[1] : af[0]);
        float zg = (m & 2) ? ((m & 1) ? ag[3] : ag[2]) : ((m & 1) ? ag[1] : ag[0]);
        float zo = (m & 2) ? ((m & 1) ? ao[3] : ao[2]) : ((m & 1) ? ao[1] : ao[0]);

        float cn = fmaf(sigmoidf_(zf), c[ug], sigmoidf_(zi) * tanhf_(zg));
        float hn = sigmoidf_(zo) * tanhf_(cn);
        c[ug] = cn;
        // cell (row, unit ug*16 + kg*4 + m): one b16 write, <=2-way banked
        hW[(w * 4 + row) * S_H + ug * 16 + kg * 4 + m] = (__bf16)hn;
    }
}

__global__ __launch_bounds__(256, 1) void lstm_kernel(const int*   __restrict__ tokens,
                                                      const float* __restrict__ embk,
                                                      const float* __restrict__ r1,
                                                      const float* __restrict__ Wd,
                                                      const float* __restrict__ bd,
                                                      float* __restrict__ out) {
    __shared__ int    tokW[16 * TS];         // 5.2 KB
    __shared__ __bf16 hW[16 * S_H];          // 2.6 KB (single buffer: read-then-write)
    __shared__ float  xst[3 * 16 * XS];      // 50.7 KB (3-slot rotation)

    const int tid  = threadIdx.x;
    const int lane = tid & 63;
    const int w    = tid >> 6;               // wave owns batch rows w*4..w*4+3
    const int n    = lane & 15;              // MFMA N col (row n&3, mirror n>>2)
    const int row  = n & 3;
    const int m    = n >> 2;                 // which acc element this lane gates
    const int kg   = lane >> 4;
    const int bb   = blockIdx.x * 16;

    // per-wave init: own token rows + own h rows (NO cross-wave sharing)
    for (int i = lane; i < 4 * T_; i += 64) {
        int r = i / T_, q = i - r * T_;
        tokW[(w * 4 + r) * TS + q] = tokens[(long)(bb + w * 4 + r) * T_ + q];
    }
    for (int i = lane; i < 4 * S_H; i += 64)
        hW[w * 4 * S_H + i] = (__bf16)0.f;

    // A-fragments: ALL of r1^T (16 col-tiles x 2 K-chunks) in registers (128 VGPR).
    // afr[ct][kc][jj] = r1[k][ct*16 + n], k = kc*32 + kg*8 + jj  (one-time load)
    bf16x8 afr[16][2];
#pragma unroll
    for (int ct = 0; ct < 16; ++ct)
#pragma unroll
        for (int kc = 0; kc < 2; ++kc) {
            bf16x8 s;
#pragma unroll
            for (int jj = 0; jj < 8; ++jj)
                s[jj] = (__bf16)r1[(kc * 32 + kg * 8 + jj) * G_ + ct * 16 + n];
            afr[ct][kc] = s;
        }

    float c[4] = {0.f, 0.f, 0.f, 0.f};
    int tk[4];

    // prologue: DMA slots 0 (t=0), 1 (t=1); prefetch tokens for t=2.
#pragma unroll
    for (int s = 0; s < 2; ++s)
#pragma unroll
        for (int r = 0; r < 4; ++r) {
            int tok = tokW[(w * 4 + r) * TS + s];
            gload16(embk + (long)tok * G_ + (lane << 2),
                    xst + s * (16 * XS) + (w * 4 + r) * XS);
        }
#pragma unroll
    for (int r = 0; r < 4; ++r) tk[r] = tokW[(w * 4 + r) * TS + 2];

    // 80 steps, slot period 3: 26 x 3 + 2 tail. No barriers anywhere.
    for (int t = 0; t < 78; t += 3) {
        lstm_step<0, 2>(t,     lane, n, kg, w, m, row, tokW, hW, xst, afr, embk, c, tk);
        lstm_step<1, 0>(t + 1, lane, n, kg, w, m, row, tokW, hW, xst, afr, embk, c, tk);
        lstm_step<2, 1>(t + 2, lane, n, kg, w, m, row, tokW, hW, xst, afr, embk, c, tk);
    }
    lstm_step<0, 2>(78, lane, n, kg, w, m, row, tokW, hW, xst, afr, embk, c, tk);
    lstm_step<1, 0>(79, lane, n, kg, w, m, row, tokW, hW, xst, afr, embk, c, tk);

    // drain DMA before kernel end
    asm volatile("s_waitcnt vmcnt(0)" ::: "memory");

    // out[b] = sigmoid(h_79[b] . Wd + bd); wave's own rows, same-wave LDS
    if (lane < 4) {
        const __bf16* hb = hW + (w * 4 + lane) * S_H;
        float s = bd[0];
#pragma unroll
        for (int u = 0; u < U_; ++u) s = fmaf((float)hb[u], Wd[u], s);
        out[bb + w * 4 + lane] = sigmoidf_(s);
    }
}

// ---------------------------------------------------------------------------
extern "C" void kernel_launch(void* const* d_in, const int* in_sizes, int n_in,
                              void* d_out, int out_size, void* d_ws, size_t ws_size,
                              hipStream_t stream) {
    const int*   tokens = (const int*)  d_in[0];
    const float* emb    = (const float*)d_in[1];
    // d_in[2..4] = k0, r0, b0 : dead in the reference (cell0 state unused)
    const float* k1     = (const float*)d_in[5];
    const float* r1     = (const float*)d_in[6];
    const float* b1     = (const float*)d_in[7];
    const float* Wd     = (const float*)d_in[8];
    const float* bd     = (const float*)d_in[9];
    float*       out    = (float*)d_out;

    float* embk = (float*)d_ws;              // V_*G_ floats = 10.24 MB

    embk_kernel<<<((V_ + 63) / 64) * 2, 256, 0, stream>>>(emb, k1, b1, embk);
    lstm_kernel<<<B_ / 16, 256, 0, stream>>>(tokens, embk, r1, Wd, bd, out);
}